// Round 1
// baseline (12204.596 us; speedup 1.0000x reference)
//
#include <hip/hip_runtime.h>
#include <stdint.h>

#define TT 336
#define BB 256

typedef __attribute__((ext_vector_type(8))) short short8;
typedef __attribute__((ext_vector_type(4))) float f32x4;
typedef __attribute__((ext_vector_type(4))) float float4v;

__device__ __forceinline__ uint16_t f2bf(float f){
    uint32_t u = __builtin_bit_cast(uint32_t, f);
    u += 0x7fffu + ((u >> 16) & 1u);   // RNE; inputs finite
    return (uint16_t)(u >> 16);
}
__device__ __forceinline__ float bf2f(uint16_t h){
    uint32_t u = ((uint32_t)h) << 16;
    return __builtin_bit_cast(float, u);
}
__device__ __forceinline__ float sigf(float x){
    return __fdividef(1.0f, 1.0f + __expf(-x));
}
__device__ __forceinline__ float tanhf_f(float x){
    return __fdividef(2.0f, 1.0f + __expf(-2.0f * x)) - 1.0f;
}

// ---------------------------------------------------------------------------
// K0: pre-pack weights into MFMA B-fragment order + bias sums.
// B-frag (16x16x32): col = lane&15, k = (lane>>4)*8 + e.
// Packed layout: [tile][kf][lane][e]  (bf16), byte stride 16/lane.
// which: 0=l0f(K=320) 1=l0r(K=320) 2=l1f W_hh(K=256) 3=l1 W_ih gemm(K=512) 4=bias
// ---------------------------------------------------------------------------
__global__ void prepack(const float* __restrict__ w_ih_l0, const float* __restrict__ w_hh_l0,
                        const float* __restrict__ w_ih_l0r, const float* __restrict__ w_hh_l0r,
                        const float* __restrict__ w_hh_l1, const float* __restrict__ w_ih_l1,
                        const float* __restrict__ b_ih_l0, const float* __restrict__ b_hh_l0,
                        const float* __restrict__ b_ih_l0r, const float* __restrict__ b_hh_l0r,
                        const float* __restrict__ b_ih_l1, const float* __restrict__ b_hh_l1,
                        uint16_t* __restrict__ Wp_l0f, uint16_t* __restrict__ Wp_l0r,
                        uint16_t* __restrict__ Wp_l1f, uint16_t* __restrict__ Wp_ih1,
                        float* __restrict__ bias)
{
    const int which = blockIdx.y;
    const int idx = blockIdx.x * 256 + threadIdx.x;
    if (which < 2) {
        if (idx >= 64*10*64*8) return;
        int e = idx & 7, lane = (idx >> 3) & 63, rem = idx >> 9;
        int kf = rem % 10, tile = rem / 10;
        int col = tile*16 + (lane & 15);
        int k   = kf*32 + (lane >> 4)*8 + e;
        const float* wi = which ? w_ih_l0r : w_ih_l0;
        const float* wh = which ? w_hh_l0r : w_hh_l0;
        float v = (k < 64) ? wi[col*64 + k] : wh[col*256 + (k - 64)];
        (which ? Wp_l0r : Wp_l0f)[idx] = f2bf(v);
    } else if (which == 2) {
        if (idx >= 64*8*64*8) return;
        int e = idx & 7, lane = (idx >> 3) & 63, rem = idx >> 9;
        int kf = rem & 7, tile = rem >> 3;
        int col = tile*16 + (lane & 15);
        int k   = kf*32 + (lane >> 4)*8 + e;
        Wp_l1f[idx] = f2bf(w_hh_l1[col*256 + k]);
    } else if (which == 3) {
        if (idx >= 64*16*64*8) return;
        int e = idx & 7, lane = (idx >> 3) & 63, rem = idx >> 9;
        int kf = rem & 15, tile = rem >> 4;
        int col = tile*16 + (lane & 15);
        int k   = kf*32 + (lane >> 4)*8 + e;
        Wp_ih1[idx] = f2bf(w_ih_l1[col*512 + k]);
    } else {
        if (idx >= 3072) return;
        int j = idx & 1023;
        float v = (idx < 1024) ? (b_ih_l0[j] + b_hh_l0[j])
                : (idx < 2048) ? (b_ih_l0r[j] + b_hh_l0r[j])
                               : (b_ih_l1[j] + b_hh_l1[j]);
        bias[idx] = v;
    }
}

// ---------------------------------------------------------------------------
// Scan kernel. LAYER=0: fused-input l0 scan (both dirs via blockIdx), writes
// l0out[t][b][dir*256+h] bf16. LAYER=1: l1 forward scan with precomputed xg
// (bias folded), writes only hlast[b][h] fp32 at t=T-1.
// Block = 256 thr (4 waves, 1 wave/SIMD). 16 batch rows/block, all 1024 gates.
// Wave w owns h-dims [w*64,(w+1)*64): tiles g*16 + w*4 + q.
// ---------------------------------------------------------------------------
template<int LAYER>
__global__ __launch_bounds__(256, 1) void scan_kernel(
    const float* __restrict__ x,
    const uint16_t* __restrict__ WpF,
    const uint16_t* __restrict__ WpR,
    const float* __restrict__ bias2,
    const uint16_t* __restrict__ xg,
    uint16_t* __restrict__ l0out,
    float* __restrict__ hlast)
{
    constexpr int KF  = (LAYER == 0) ? 10 : 8;   // K/32
    constexpr int PKF = KF / 2;
    constexpr int KH0 = (LAYER == 0) ? 2 : 0;    // first h-fragment index

    const int tid = threadIdx.x;
    const int lane = tid & 63, wv = tid >> 6;
    const int lrow = lane & 15, lkg = lane >> 4;
    int dir, mch;
    if (LAYER == 0) { dir = blockIdx.x >> 4; mch = blockIdx.x & 15; }
    else            { dir = 0;               mch = blockIdx.x; }
    const int b0 = mch * 16;

    const uint16_t* Wp = (LAYER == 0 && dir) ? WpR : WpF;
    const char* wlane = (const char*)Wp + (size_t)lane * 16;

    __shared__ __align__(16) uint16_t hb[16 * 256];  // h state, XOR-swizzled
    __shared__ __align__(16) uint16_t xb[16 * 64];   // x_t staging (LAYER0)
    char* hbc = (char*)hb;
    char* xbc = (char*)xb;

    for (int i = tid; i < 1024; i += 256) ((uint64_t*)hb)[i] = 0ull; // h0 = 0

    float biasreg[16];
    if (LAYER == 0) {
        const float* bs = bias2 + dir * 1024;
        #pragma unroll
        for (int g = 0; g < 4; ++g)
            #pragma unroll
            for (int q = 0; q < 4; ++q)
                biasreg[g*4+q] = bs[g*256 + wv*64 + q*16 + lrow];
    }

    uint2 xgv[16];
    if (LAYER == 1) {   // prefetch xg for t=0
        const char* xgb = (const char*)xg + (size_t)mch * 32768 + (size_t)lane * 8;
        #pragma unroll
        for (int g = 0; g < 4; ++g)
            #pragma unroll
            for (int q = 0; q < 4; ++q) {
                int tile = g*16 + wv*4 + q;
                xgv[g*4+q] = *(const uint2*)(xgb + tile * 512);
            }
    }

    if (LAYER == 0) {   // stage x for first step
        const int t0 = dir ? (TT - 1) : 0;
        const int row = tid >> 4, k0 = (tid & 15) * 4;
        float4v v = *(const float4v*)(x + ((size_t)(b0 + row) * TT + t0) * 64 + k0);
        uint32_t lo = (uint32_t)f2bf(v[0]) | ((uint32_t)f2bf(v[1]) << 16);
        uint32_t hi = (uint32_t)f2bf(v[2]) | ((uint32_t)f2bf(v[3]) << 16);
        int a = (row*128 + k0*2) ^ ((row & 7) << 4);
        *(uint32_t*)(xbc + a)     = lo;
        *(uint32_t*)(xbc + a + 4) = hi;
    }

    float cst[16];
    #pragma unroll
    for (int i = 0; i < 16; ++i) cst[i] = 0.0f;

    __syncthreads();

    for (int step = 0; step < TT; ++step) {
        const int t = (LAYER == 0 && dir) ? (TT - 1 - step) : step;

        // ---- A-phase: read activation fragments (A: row=lane&15, k=(lane>>4)*8+e)
        short8 afr[KF];
        if (LAYER == 0) {
            #pragma unroll
            for (int kf = 0; kf < 2; ++kf) {
                int a = (lrow*128 + (kf*32 + lkg*8)*2) ^ ((lrow & 7) << 4);
                afr[kf] = *(const short8*)(xbc + a);
            }
        }
        #pragma unroll
        for (int kf = KH0; kf < KF; ++kf) {
            int a = (lrow*512 + ((kf - KH0)*32 + lkg*8)*2) ^ ((lrow & 7) << 4);
            afr[kf] = *(const short8*)(hbc + a);
        }
        __syncthreads();   // all reads of hb/xb done

        // ---- acc init (D: col=lane&15, row=(lane>>4)*4+reg)
        f32x4 acc[4][4];
        if (LAYER == 0) {
            #pragma unroll
            for (int g = 0; g < 4; ++g)
                #pragma unroll
                for (int q = 0; q < 4; ++q) {
                    float bv = biasreg[g*4+q];
                    acc[g][q] = (f32x4){bv, bv, bv, bv};
                }
        } else {
            #pragma unroll
            for (int g = 0; g < 4; ++g)
                #pragma unroll
                for (int q = 0; q < 4; ++q) {
                    uint2 v = xgv[g*4+q];
                    acc[g][q][0] = bf2f((uint16_t)(v.x & 0xffffu));
                    acc[g][q][1] = bf2f((uint16_t)(v.x >> 16));
                    acc[g][q][2] = bf2f((uint16_t)(v.y & 0xffffu));
                    acc[g][q][3] = bf2f((uint16_t)(v.y >> 16));
                }
        }

        // ---- issue next-step prefetches (consumed well after ~HBM latency)
        float4v xload;
        const bool do_x = (LAYER == 0) && (step + 1 < TT);
        if (do_x) {
            const int tn = dir ? (t - 1) : (t + 1);
            const int row = tid >> 4, k0 = (tid & 15) * 4;
            xload = *(const float4v*)(x + ((size_t)(b0 + row) * TT + tn) * 64 + k0);
        }
        if (LAYER == 1 && step + 1 < TT) {
            const char* xgb = (const char*)xg + (size_t)((step + 1) * 16 + mch) * 32768 + (size_t)lane * 8;
            #pragma unroll
            for (int g = 0; g < 4; ++g)
                #pragma unroll
                for (int q = 0; q < 4; ++q) {
                    int tile = g*16 + wv*4 + q;
                    xgv[g*4+q] = *(const uint2*)(xgb + tile * 512);
                }
        }

        // ---- weight-streamed MFMA: 8 chunks (gate g, half p), 3-deep rolling buf
        short8 wbuf[3][4][PKF];
        #pragma unroll
        for (int c = 0; c < 3; ++c) {
            const int g2 = c >> 1, p2 = c & 1;
            #pragma unroll
            for (int q = 0; q < 4; ++q) {
                const int tile = g2*16 + wv*4 + q;
                #pragma unroll
                for (int kk = 0; kk < PKF; ++kk)
                    wbuf[c][q][kk] = *(const short8*)(wlane + (size_t)(tile*KF + p2*PKF + kk) * 1024);
            }
        }
        #pragma unroll
        for (int ch = 0; ch < 8; ++ch) {
            const int g = ch >> 1, p = ch & 1;
            #pragma unroll
            for (int kk = 0; kk < PKF; ++kk) {
                const int kf = p*PKF + kk;
                #pragma unroll
                for (int q = 0; q < 4; ++q)
                    acc[g][q] = __builtin_amdgcn_mfma_f32_16x16x32_bf16(
                        afr[kf], wbuf[ch % 3][q][kk], acc[g][q], 0, 0, 0);
            }
            if (ch < 5) {
                const int c2 = ch + 3, g2 = c2 >> 1, p2 = c2 & 1;
                #pragma unroll
                for (int q = 0; q < 4; ++q) {
                    const int tile = g2*16 + wv*4 + q;
                    #pragma unroll
                    for (int kk = 0; kk < PKF; ++kk)
                        wbuf[c2 % 3][q][kk] = *(const short8*)(wlane + (size_t)(tile*KF + p2*PKF + kk) * 1024);
                }
            }
        }

        // ---- write-late x staging (T14)
        if (do_x) {
            const int row = tid >> 4, k0 = (tid & 15) * 4;
            uint32_t lo = (uint32_t)f2bf(xload[0]) | ((uint32_t)f2bf(xload[1]) << 16);
            uint32_t hi = (uint32_t)f2bf(xload[2]) | ((uint32_t)f2bf(xload[3]) << 16);
            int a = (row*128 + k0*2) ^ ((row & 7) << 4);
            *(uint32_t*)(xbc + a)     = lo;
            *(uint32_t*)(xbc + a + 4) = hi;
        }

        // ---- activations, state update, h writes
        #pragma unroll
        for (int q = 0; q < 4; ++q) {
            #pragma unroll
            for (int r = 0; r < 4; ++r) {
                float iv = sigf(acc[0][q][r]);
                float fv = sigf(acc[1][q][r]);
                float gv = tanhf_f(acc[2][q][r]);
                float ov = sigf(acc[3][q][r]);
                float cn = fv * cst[q*4+r] + iv * gv;
                cst[q*4+r] = cn;
                float hv = ov * tanhf_f(cn);
                uint16_t hbits = f2bf(hv);
                const int row  = lkg*4 + r;
                const int hdim = wv*64 + q*16 + lrow;
                *(uint16_t*)(hbc + ((row*512 + hdim*2) ^ ((row & 7) << 4))) = hbits;
                if (LAYER == 0) {
                    l0out[((size_t)t * 256 + (size_t)(b0 + row)) * 512 + dir*256 + hdim] = hbits;
                } else if (step == TT - 1) {
                    hlast[(size_t)(b0 + row) * 256 + hdim] = hv;
                }
            }
        }
        __syncthreads();   // h visible for next step
    }
}

// ---------------------------------------------------------------------------
// K2: xg_l1f = l0out[BT,512] @ W_ih_l1^T + (b_ih+b_hh), written bf16 directly
// in the scan's D-fragment packed layout [t*16+mch][tile][lane][reg].
// ---------------------------------------------------------------------------
__global__ __launch_bounds__(256, 2) void gemm_xg1(
    const uint16_t* __restrict__ l0out,
    const uint16_t* __restrict__ Wp,
    const float* __restrict__ bias,
    uint16_t* __restrict__ xg1p)
{
    __shared__ __align__(16) uint16_t ab[64 * 512];   // 64 KB A tile
    char* abc = (char*)ab;
    const int tid = threadIdx.x;
    const int lane = tid & 63, wv = tid >> 6;
    const int lrow = lane & 15, lkg = lane >> 4;
    const int wg = blockIdx.x;
    const size_t rowbase = (size_t)wg * 64;

    #pragma unroll
    for (int i = 0; i < 16; ++i) {
        int cch = tid + i * 256;
        int row = cch >> 6, kc = cch & 63;
        short8 v = *(const short8*)(l0out + (rowbase + row) * 512 + kc * 8);
        int a = (row*1024 + kc*16) ^ ((row & 7) << 4);
        *(short8*)(abc + a) = v;
    }
    __syncthreads();

    float biasreg[16];
    #pragma unroll
    for (int j = 0; j < 16; ++j) biasreg[j] = bias[wv*256 + j*16 + lrow];

    const char* wlane = (const char*)Wp + (size_t)lane * 16;

    for (int j = 0; j < 16; ++j) {
        const int tile = wv*16 + j;
        short8 wfr[16];
        #pragma unroll
        for (int kf = 0; kf < 16; ++kf)
            wfr[kf] = *(const short8*)(wlane + (size_t)(tile*16 + kf) * 1024);
        f32x4 acc[4];
        #pragma unroll
        for (int mt = 0; mt < 4; ++mt) {
            float bv = biasreg[j];
            acc[mt] = (f32x4){bv, bv, bv, bv};
        }
        #pragma unroll
        for (int kf = 0; kf < 16; ++kf) {
            #pragma unroll
            for (int mt = 0; mt < 4; ++mt) {
                int row = mt*16 + lrow;
                int a = (row*1024 + kf*64 + lkg*16) ^ ((row & 7) << 4);
                short8 av = *(const short8*)(abc + a);
                acc[mt] = __builtin_amdgcn_mfma_f32_16x16x32_bf16(av, wfr[kf], acc[mt], 0, 0, 0);
            }
        }
        #pragma unroll
        for (int mt = 0; mt < 4; ++mt) {
            uint2 o;
            o.x = (uint32_t)f2bf(acc[mt][0]) | ((uint32_t)f2bf(acc[mt][1]) << 16);
            o.y = (uint32_t)f2bf(acc[mt][2]) | ((uint32_t)f2bf(acc[mt][3]) << 16);
            *(uint2*)((char*)xg1p + ((size_t)(wg*4 + mt) * 64 + tile) * 512 + (size_t)lane * 8) = o;
        }
    }
}

// ---------------------------------------------------------------------------
// K4: layer-1 reverse at t=T-1 is ONE LSTM step from zero state (c=i*g), then
// the final FC: out[b] = fc_w[0:256]·h_f + fc_w[256:512]·h_r + fc_b.
// ---------------------------------------------------------------------------
__global__ __launch_bounds__(256) void l1r_fc(
    const uint16_t* __restrict__ l0out,
    const float* __restrict__ w_ih,
    const float* __restrict__ b_ih,
    const float* __restrict__ b_hh,
    const float* __restrict__ hlast,
    const float* __restrict__ fc_w,
    const float* __restrict__ fc_b,
    float* __restrict__ out)
{
    __shared__ __align__(16) float x1[512];
    __shared__ float red[256];
    const int tid = threadIdx.x;
    const int b = blockIdx.x;
    for (int i = tid; i < 512; i += 256)
        x1[i] = bf2f(l0out[((size_t)(TT - 1) * 256 + b) * 512 + i]);
    __syncthreads();
    float di = b_ih[tid]       + b_hh[tid];         // i gate (col tid)
    float dg = b_ih[512 + tid] + b_hh[512 + tid];   // g gate
    float dv = b_ih[768 + tid] + b_hh[768 + tid];   // o gate  (f unused: c0=0)
    const float4v* wi = (const float4v*)(w_ih + (size_t)tid * 512);
    const float4v* wg = (const float4v*)(w_ih + (size_t)(512 + tid) * 512);
    const float4v* wo = (const float4v*)(w_ih + (size_t)(768 + tid) * 512);
    for (int k = 0; k < 128; ++k) {
        float4v xv = *(const float4v*)(x1 + k * 4);
        float4v a = wi[k], bq = wg[k], cq = wo[k];
        di += a[0]*xv[0] + a[1]*xv[1] + a[2]*xv[2] + a[3]*xv[3];
        dg += bq[0]*xv[0] + bq[1]*xv[1] + bq[2]*xv[2] + bq[3]*xv[3];
        dv += cq[0]*xv[0] + cq[1]*xv[1] + cq[2]*xv[2] + cq[3]*xv[3];
    }
    float cv = sigf(di) * tanhf_f(dg);
    float hr = sigf(dv) * tanhf_f(cv);
    float p = fc_w[tid] * hlast[(size_t)b * 256 + tid] + fc_w[256 + tid] * hr;
    red[tid] = p;
    __syncthreads();
    #pragma unroll
    for (int s = 128; s > 0; s >>= 1) {
        if (tid < s) red[tid] += red[tid + s];
        __syncthreads();
    }
    if (tid == 0) out[b] = red[0] + fc_b[0];
}

// ---------------------------------------------------------------------------
extern "C" void kernel_launch(void* const* d_in, const int* in_sizes, int n_in,
                              void* d_out, int out_size, void* d_ws, size_t ws_size,
                              hipStream_t stream)
{
    const float* x        = (const float*)d_in[0];
    const float* w_ih_l0  = (const float*)d_in[1];
    const float* w_hh_l0  = (const float*)d_in[2];
    const float* b_ih_l0  = (const float*)d_in[3];
    const float* b_hh_l0  = (const float*)d_in[4];
    const float* w_ih_l0r = (const float*)d_in[5];
    const float* w_hh_l0r = (const float*)d_in[6];
    const float* b_ih_l0r = (const float*)d_in[7];
    const float* b_hh_l0r = (const float*)d_in[8];
    const float* w_ih_l1  = (const float*)d_in[9];
    const float* w_hh_l1  = (const float*)d_in[10];
    const float* b_ih_l1  = (const float*)d_in[11];
    const float* b_hh_l1  = (const float*)d_in[12];
    const float* w_ih_l1r = (const float*)d_in[13];
    const float* b_ih_l1r = (const float*)d_in[15];
    const float* b_hh_l1r = (const float*)d_in[16];
    const float* fc_w     = (const float*)d_in[17];
    const float* fc_b     = (const float*)d_in[18];
    float* out = (float*)d_out;
    (void)in_sizes; (void)n_in; (void)out_size; (void)ws_size;

    // workspace carve-up (~255 MB total)
    char* p = (char*)d_ws;
    size_t o = 0;
    auto take = [&](size_t bytes) -> char* {
        char* r = p + o; o += (bytes + 255) & ~(size_t)255; return r;
    };
    uint16_t* Wp_l0f = (uint16_t*)take(64*10*64*8 * 2);      // 640 KB
    uint16_t* Wp_l0r = (uint16_t*)take(64*10*64*8 * 2);      // 640 KB
    uint16_t* Wp_l1f = (uint16_t*)take(64*8*64*8 * 2);       // 512 KB
    uint16_t* Wp_ih1 = (uint16_t*)take(64*16*64*8 * 2);      // 1 MB
    float*    bias   = (float*)take(3 * 1024 * 4);           // 12 KB
    uint16_t* l0out  = (uint16_t*)take((size_t)TT*BB*512*2); // 88 MB bf16
    uint16_t* xg1p   = (uint16_t*)take((size_t)TT*16*64*64*4*2); // 176 MB bf16
    float*    hlast  = (float*)take(BB * 256 * 4);           // 256 KB

    prepack<<<dim3(2048, 5, 1), 256, 0, stream>>>(
        w_ih_l0, w_hh_l0, w_ih_l0r, w_hh_l0r, w_hh_l1, w_ih_l1,
        b_ih_l0, b_hh_l0, b_ih_l0r, b_hh_l0r, b_ih_l1, b_hh_l1,
        Wp_l0f, Wp_l0r, Wp_l1f, Wp_ih1, bias);

    // layer 0, both directions concurrently (32 wgs)
    scan_kernel<0><<<32, 256, 0, stream>>>(x, Wp_l0f, Wp_l0r, bias, nullptr, l0out, nullptr);

    // layer-1 input projection (full-chip GEMM)
    gemm_xg1<<<(TT * BB) / 64, 256, 0, stream>>>(l0out, Wp_ih1, bias + 2048, xg1p);

    // layer 1 forward scan (16 wgs) -> hlast
    scan_kernel<1><<<16, 256, 0, stream>>>(nullptr, Wp_l1f, nullptr, nullptr, xg1p, nullptr, hlast);

    // layer-1 reverse single step + FC
    l1r_fc<<<BB, 256, 0, stream>>>(l0out, w_ih_l1r, b_ih_l1r, b_hh_l1r, hlast, fc_w, fc_b, out);
}

// Round 3
// 3762.449 us; speedup vs baseline: 3.2438x; 3.2438x over previous
//
#include <hip/hip_runtime.h>
#include <stdint.h>

#define TT 336
#define BB 256

typedef __attribute__((ext_vector_type(8))) short short8;
typedef __attribute__((ext_vector_type(4))) float f32x4;
typedef __attribute__((ext_vector_type(4))) float float4v;
typedef __attribute__((ext_vector_type(2))) unsigned long long ull2;

__device__ __forceinline__ uint16_t f2bf(float f){
    uint32_t u = __builtin_bit_cast(uint32_t, f);
    u += 0x7fffu + ((u >> 16) & 1u);
    return (uint16_t)(u >> 16);
}
__device__ __forceinline__ float bf2f(uint16_t h){
    uint32_t u = ((uint32_t)h) << 16;
    return __builtin_bit_cast(float, u);
}
__device__ __forceinline__ float sigf(float x){
    return __fdividef(1.0f, 1.0f + __expf(-x));
}
__device__ __forceinline__ float tanhf_f(float x){
    return __fdividef(2.0f, 1.0f + __expf(-2.0f * x)) - 1.0f;
}

// ---------------------------------------------------------------------------
// K0: pre-pack weights into MFMA B-fragment order + bias sums.
// B-frag (16x16x32): col = lane&15, k = (lane>>4)*8 + e.
// Packed layout: [tile][kf][lane][e]  (bf16), byte stride 16/lane.
// ---------------------------------------------------------------------------
__global__ void prepack(const float* __restrict__ w_ih_l0, const float* __restrict__ w_hh_l0,
                        const float* __restrict__ w_ih_l0r, const float* __restrict__ w_hh_l0r,
                        const float* __restrict__ w_hh_l1, const float* __restrict__ w_ih_l1,
                        const float* __restrict__ b_ih_l0, const float* __restrict__ b_hh_l0,
                        const float* __restrict__ b_ih_l0r, const float* __restrict__ b_hh_l0r,
                        const float* __restrict__ b_ih_l1, const float* __restrict__ b_hh_l1,
                        uint16_t* __restrict__ Wp_l0f, uint16_t* __restrict__ Wp_l0r,
                        uint16_t* __restrict__ Wp_l1f, uint16_t* __restrict__ Wp_ih1,
                        float* __restrict__ bias)
{
    const int which = blockIdx.y;
    const int idx = blockIdx.x * 256 + threadIdx.x;
    if (which < 2) {
        if (idx >= 64*10*64*8) return;
        int e = idx & 7, lane = (idx >> 3) & 63, rem = idx >> 9;
        int kf = rem % 10, tile = rem / 10;
        int col = tile*16 + (lane & 15);
        int k   = kf*32 + (lane >> 4)*8 + e;
        const float* wi = which ? w_ih_l0r : w_ih_l0;
        const float* wh = which ? w_hh_l0r : w_hh_l0;
        float v = (k < 64) ? wi[col*64 + k] : wh[col*256 + (k - 64)];
        (which ? Wp_l0r : Wp_l0f)[idx] = f2bf(v);
    } else if (which == 2) {
        if (idx >= 64*8*64*8) return;
        int e = idx & 7, lane = (idx >> 3) & 63, rem = idx >> 9;
        int kf = rem & 7, tile = rem >> 3;
        int col = tile*16 + (lane & 15);
        int k   = kf*32 + (lane >> 4)*8 + e;
        Wp_l1f[idx] = f2bf(w_hh_l1[col*256 + k]);
    } else if (which == 3) {
        if (idx >= 64*16*64*8) return;
        int e = idx & 7, lane = (idx >> 3) & 63, rem = idx >> 9;
        int kf = rem & 15, tile = rem >> 4;
        int col = tile*16 + (lane & 15);
        int k   = kf*32 + (lane >> 4)*8 + e;
        Wp_ih1[idx] = f2bf(w_ih_l1[col*512 + k]);
    } else {
        if (idx >= 3072) return;
        int j = idx & 1023;
        float v = (idx < 1024) ? (b_ih_l0[j] + b_hh_l0[j])
                : (idx < 2048) ? (b_ih_l0r[j] + b_hh_l0r[j])
                               : (b_ih_l1[j] + b_hh_l1[j]);
        bias[idx] = v;
    }
}

__global__ void zero_flags(uint32_t* __restrict__ flags) {
    if (threadIdx.x < 96) flags[threadIdx.x] = 0;
}

// ---------------------------------------------------------------------------
// Pairwise gate-split scan. Each (dir, 16-row batch tile) is served by a PAIR
// of wgs: half m owns gate-dims [m*128, m*128+128) of each gate. Weights are
// fully register-resident (wfx/wfo/wfp, static indices). Per step the halves
// exchange their 128 h-dims via global memory in A-fragment order:
//   publish = agent-scope relaxed atomic u16 stores (complete at coherence pt)
//   consume = agent-scope relaxed atomic u64 loads (bypass stale L1/L2)
// ordered by a release/acquire flag (monotonic counter, parity double-buffer,
// lag-2 reuse is race-free: writer of parity p at step s+2 waits flag>=s+3
// which the partner publishes only after its step-s+1 read of parity p).
// wg = 512 threads = 8 waves (2/SIMD, 1 wg/CU -> 256 VGPR budget).
// ---------------------------------------------------------------------------
template<int LAYER>
__global__ __launch_bounds__(512, 2) void scan_pair(
    const float* __restrict__ x,
    const uint16_t* __restrict__ WpF,
    const uint16_t* __restrict__ WpR,
    const float* __restrict__ bias2,
    const uint16_t* __restrict__ xg,
    uint16_t* __restrict__ l0out,
    float* __restrict__ hlast,
    uint16_t* __restrict__ exch,     // [nwg][2 parity][2048] u16 (A-frag order)
    uint32_t* __restrict__ flags)    // [nwg] publish counters
{
    constexpr int KF  = (LAYER == 0) ? 10 : 8;
    constexpr int KH0 = (LAYER == 0) ? 2 : 0;   // first h kf index

    const int tid  = threadIdx.x;
    const int lane = tid & 63, wv = tid >> 6;        // wave 0..7
    const int lrow = lane & 15, lkg = lane >> 4;
    const int bid  = blockIdx.x;
    const int m    = bid & 1;                        // half
    const int pairId = bid >> 1;
    int dir, mch;
    if (LAYER == 0) { dir = pairId >> 4; mch = pairId & 15; }
    else            { dir = 0;           mch = pairId; }
    const int b0   = mch * 16;
    const int hd0  = m * 128;
    const int dimLocal = wv * 16 + lrow;             // owned dim within half

    // ---- register-resident weights (static-index arrays; rule #20)
    const uint16_t* Wp = (LAYER == 0 && dir) ? WpR : WpF;
    const char* wlane = (const char*)Wp + (size_t)lane * 16;
    short8 wfx[4][2];            // L0 only: x-projection kf 0,1
    short8 wfo[4][4];            // own-half h kfs
    short8 wfp[4][4];            // partner-half h kfs
    #pragma unroll
    for (int g = 0; g < 4; ++g) {
        const int tile = g*16 + m*8 + wv;
        if (LAYER == 0) {
            #pragma unroll
            for (int k = 0; k < 2; ++k)
                wfx[g][k] = *(const short8*)(wlane + (size_t)(tile*KF + k) * 1024);
        }
        #pragma unroll
        for (int j = 0; j < 4; ++j) {
            wfo[g][j] = *(const short8*)(wlane + (size_t)(tile*KF + KH0 + m*4 + j) * 1024);
            wfp[g][j] = *(const short8*)(wlane + (size_t)(tile*KF + KH0 + (1-m)*4 + j) * 1024);
        }
    }

    float biasreg[4];
    if (LAYER == 0) {
        const float* bs = bias2 + dir * 1024;
        #pragma unroll
        for (int g = 0; g < 4; ++g)
            biasreg[g] = bs[g*256 + hd0 + dimLocal];
    }

    uint16_t* exMine = exch + (size_t)bid * 4096;
    const uint16_t* exPart = exch + (size_t)(bid ^ 1) * 4096;
    uint32_t* fMine = flags + bid;
    uint32_t* fPart = flags + (bid ^ 1);

    __shared__ __align__(16) uint16_t hb[16 * 128];  // own-half h, XOR-swizzled
    __shared__ __align__(16) uint16_t xb[16 * 64];   // x_t staging (LAYER0)
    char* hbc = (char*)hb;
    char* xbc = (char*)xb;

    ((uint64_t*)hb)[tid] = 0ull;           // h0 = 0 (512 u64 = FULL 4096 B)
    ((uint64_t*)exMine)[tid] = 0ull;       // initial publish: zeros into parity 0

    if (LAYER == 0 && tid < 256) {         // stage x for first step
        const int t0 = dir ? (TT - 1) : 0;
        const int row = tid >> 4, k0 = (tid & 15) * 4;
        float4v v = *(const float4v*)(x + ((size_t)(b0 + row) * TT + t0) * 64 + k0);
        uint32_t lo = (uint32_t)f2bf(v[0]) | ((uint32_t)f2bf(v[1]) << 16);
        uint32_t hi = (uint32_t)f2bf(v[2]) | ((uint32_t)f2bf(v[3]) << 16);
        int a = (row*128 + k0*2) ^ ((row & 7) << 4);
        *(uint32_t*)(xbc + a)     = lo;
        *(uint32_t*)(xbc + a + 4) = hi;
    }

    uint2 xgv[4], xgn[4];
    if (LAYER == 1) {                      // prefetch xg for step 0
        #pragma unroll
        for (int g = 0; g < 4; ++g) {
            const int tile = g*16 + m*8 + wv;
            xgv[g] = *(const uint2*)((const char*)xg + ((size_t)mch * 64 + tile) * 512 + (size_t)lane * 8);
        }
    }

    float cst[4];
    #pragma unroll
    for (int i = 0; i < 4; ++i) cst[i] = 0.0f;

    __syncthreads();                        // drains stores (vmcnt 0) + barrier
    if (tid == 0)
        __hip_atomic_store(fMine, 1u, __ATOMIC_RELEASE, __HIP_MEMORY_SCOPE_AGENT);

    for (int step = 0; step < TT; ++step) {
        const int t = (LAYER == 0 && dir) ? (TT - 1 - step) : step;

        // ---- acc init
        f32x4 acc[4];
        if (LAYER == 0) {
            #pragma unroll
            for (int g = 0; g < 4; ++g) {
                float bv = biasreg[g];
                acc[g] = (f32x4){bv, bv, bv, bv};
            }
        } else {
            #pragma unroll
            for (int g = 0; g < 4; ++g) {
                uint2 v = xgv[g];
                acc[g][0] = bf2f((uint16_t)(v.x & 0xffffu));
                acc[g][1] = bf2f((uint16_t)(v.x >> 16));
                acc[g][2] = bf2f((uint16_t)(v.y & 0xffffu));
                acc[g][3] = bf2f((uint16_t)(v.y >> 16));
            }
        }

        // ---- local MFMAs: x-frags (L0) + own-half h frags
        if (LAYER == 0) {
            #pragma unroll
            for (int kf = 0; kf < 2; ++kf) {
                int a = (lrow*128 + (kf*32 + lkg*8)*2) ^ ((lrow & 7) << 4);
                short8 av = *(const short8*)(xbc + a);
                #pragma unroll
                for (int g = 0; g < 4; ++g)
                    acc[g] = __builtin_amdgcn_mfma_f32_16x16x32_bf16(av, wfx[g][kf], acc[g], 0, 0, 0);
            }
        }
        #pragma unroll
        for (int j = 0; j < 4; ++j) {
            int a = (lrow*256 + (j*32 + lkg*8)*2) ^ ((lrow & 7) << 4);
            short8 av = *(const short8*)(hbc + a);
            #pragma unroll
            for (int g = 0; g < 4; ++g)
                acc[g] = __builtin_amdgcn_mfma_f32_16x16x32_bf16(av, wfo[g][j], acc[g], 0, 0, 0);
        }

        // ---- next-step prefetches (latency hidden under partner wait)
        float4v xload;
        const bool do_x = (LAYER == 0) && (step + 1 < TT);
        if (do_x && tid < 256) {
            const int tn = dir ? (t - 1) : (t + 1);
            const int row = tid >> 4, k0 = (tid & 15) * 4;
            xload = *(const float4v*)(x + ((size_t)(b0 + row) * TT + tn) * 64 + k0);
        }
        if (LAYER == 1 && step + 1 < TT) {
            #pragma unroll
            for (int g = 0; g < 4; ++g) {
                const int tile = g*16 + m*8 + wv;
                xgn[g] = *(const uint2*)((const char*)xg + ((size_t)((step + 1) * 16 + mch) * 64 + tile) * 512 + (size_t)lane * 8);
            }
        }

        // ---- wait for partner's h_{t-1}, then partner-half MFMAs from exch
        if (tid == 0) {
            while (__hip_atomic_load(fPart, __ATOMIC_RELAXED, __HIP_MEMORY_SCOPE_AGENT) < (uint32_t)(step + 1)) {}
            (void)__hip_atomic_load(fPart, __ATOMIC_ACQUIRE, __HIP_MEMORY_SCOPE_AGENT);
        }
        __syncthreads();    // also protects hb: reads above vs writes below
        {
            const uint16_t* ep = exPart + (size_t)(step & 1) * 2048;
            #pragma unroll
            for (int j = 0; j < 4; ++j) {
                const unsigned long long* q =
                    (const unsigned long long*)(ep + j*512 + lane*8);
                ull2 tv;
                tv[0] = __hip_atomic_load(q,     __ATOMIC_RELAXED, __HIP_MEMORY_SCOPE_AGENT);
                tv[1] = __hip_atomic_load(q + 1, __ATOMIC_RELAXED, __HIP_MEMORY_SCOPE_AGENT);
                short8 av = __builtin_bit_cast(short8, tv);
                #pragma unroll
                for (int g = 0; g < 4; ++g)
                    acc[g] = __builtin_amdgcn_mfma_f32_16x16x32_bf16(av, wfp[g][j], acc[g], 0, 0, 0);
            }
        }

        // ---- activations + state update + publishes
        const int kfr = dimLocal >> 5, rem = dimLocal & 31;
        uint16_t* exw = exMine + (size_t)((step + 1) & 1) * 2048 + kfr*512 + (rem >> 3)*128 + (rem & 7);
        #pragma unroll
        for (int r = 0; r < 4; ++r) {
            float iv = sigf(acc[0][r]);
            float fv = sigf(acc[1][r]);
            float gv = tanhf_f(acc[2][r]);
            float ov = sigf(acc[3][r]);
            float cn = fv * cst[r] + iv * gv;
            cst[r] = cn;
            float hv = ov * tanhf_f(cn);
            uint16_t hbits = f2bf(hv);
            const int row = lkg*4 + r;
            *(uint16_t*)(hbc + ((row*256 + dimLocal*2) ^ ((row & 7) << 4))) = hbits;
            if (step + 1 < TT)
                __hip_atomic_store((unsigned short*)(exw + row * 8), (unsigned short)hbits,
                                   __ATOMIC_RELAXED, __HIP_MEMORY_SCOPE_AGENT);
            if (LAYER == 0) {
                l0out[((size_t)t * 256 + (size_t)(b0 + row)) * 512 + dir*256 + hd0 + dimLocal] = hbits;
            } else if (step == TT - 1) {
                hlast[(size_t)(b0 + row) * 256 + hd0 + dimLocal] = hv;
            }
        }

        // ---- write-late x staging
        if (do_x && tid < 256) {
            const int row = tid >> 4, k0 = (tid & 15) * 4;
            uint32_t lo = (uint32_t)f2bf(xload[0]) | ((uint32_t)f2bf(xload[1]) << 16);
            uint32_t hi = (uint32_t)f2bf(xload[2]) | ((uint32_t)f2bf(xload[3]) << 16);
            int a = (row*128 + k0*2) ^ ((row & 7) << 4);
            *(uint32_t*)(xbc + a)     = lo;
            *(uint32_t*)(xbc + a + 4) = hi;
        }
        if (LAYER == 1) {
            #pragma unroll
            for (int g = 0; g < 4; ++g) xgv[g] = xgn[g];
        }

        __syncthreads();    // all exch/hb stores drained (vmcnt 0) + barrier
        if (tid == 0 && step + 1 < TT)
            __hip_atomic_store(fMine, (uint32_t)(step + 2), __ATOMIC_RELEASE, __HIP_MEMORY_SCOPE_AGENT);
    }
}

// ---------------------------------------------------------------------------
// K2: xg_l1f = l0out[BT,512] @ W_ih_l1^T + (b_ih+b_hh), bf16, D-frag packed.
// ---------------------------------------------------------------------------
__global__ __launch_bounds__(256, 2) void gemm_xg1(
    const uint16_t* __restrict__ l0out,
    const uint16_t* __restrict__ Wp,
    const float* __restrict__ bias,
    uint16_t* __restrict__ xg1p)
{
    __shared__ __align__(16) uint16_t ab[64 * 512];
    char* abc = (char*)ab;
    const int tid = threadIdx.x;
    const int lane = tid & 63, wv = tid >> 6;
    const int lrow = lane & 15, lkg = lane >> 4;
    const int wg = blockIdx.x;
    const size_t rowbase = (size_t)wg * 64;

    #pragma unroll
    for (int i = 0; i < 16; ++i) {
        int cch = tid + i * 256;
        int row = cch >> 6, kc = cch & 63;
        short8 v = *(const short8*)(l0out + (rowbase + row) * 512 + kc * 8);
        int a = (row*1024 + kc*16) ^ ((row & 7) << 4);
        *(short8*)(abc + a) = v;
    }
    __syncthreads();

    float biasreg[16];
    #pragma unroll
    for (int j = 0; j < 16; ++j) biasreg[j] = bias[wv*256 + j*16 + lrow];

    const char* wlane = (const char*)Wp + (size_t)lane * 16;

    for (int j = 0; j < 16; ++j) {
        const int tile = wv*16 + j;
        short8 wfr[16];
        #pragma unroll
        for (int kf = 0; kf < 16; ++kf)
            wfr[kf] = *(const short8*)(wlane + (size_t)(tile*16 + kf) * 1024);
        f32x4 acc[4];
        #pragma unroll
        for (int mt = 0; mt < 4; ++mt) {
            float bv = biasreg[j];
            acc[mt] = (f32x4){bv, bv, bv, bv};
        }
        #pragma unroll
        for (int kf = 0; kf < 16; ++kf) {
            #pragma unroll
            for (int mt = 0; mt < 4; ++mt) {
                int row = mt*16 + lrow;
                int a = (row*1024 + kf*64 + lkg*16) ^ ((row & 7) << 4);
                short8 av = *(const short8*)(abc + a);
                acc[mt] = __builtin_amdgcn_mfma_f32_16x16x32_bf16(av, wfr[kf], acc[mt], 0, 0, 0);
            }
        }
        #pragma unroll
        for (int mt = 0; mt < 4; ++mt) {
            uint2 o;
            o.x = (uint32_t)f2bf(acc[mt][0]) | ((uint32_t)f2bf(acc[mt][1]) << 16);
            o.y = (uint32_t)f2bf(acc[mt][2]) | ((uint32_t)f2bf(acc[mt][3]) << 16);
            *(uint2*)((char*)xg1p + ((size_t)(wg*4 + mt) * 64 + tile) * 512 + (size_t)lane * 8) = o;
        }
    }
}

// ---------------------------------------------------------------------------
// K4: layer-1 reverse at t=T-1 is ONE LSTM step from zero state, then FC.
// ---------------------------------------------------------------------------
__global__ __launch_bounds__(256) void l1r_fc(
    const uint16_t* __restrict__ l0out,
    const float* __restrict__ w_ih,
    const float* __restrict__ b_ih,
    const float* __restrict__ b_hh,
    const float* __restrict__ hlast,
    const float* __restrict__ fc_w,
    const float* __restrict__ fc_b,
    float* __restrict__ out)
{
    __shared__ __align__(16) float x1[512];
    __shared__ float red[256];
    const int tid = threadIdx.x;
    const int b = blockIdx.x;
    for (int i = tid; i < 512; i += 256)
        x1[i] = bf2f(l0out[((size_t)(TT - 1) * 256 + b) * 512 + i]);
    __syncthreads();
    float di = b_ih[tid]       + b_hh[tid];
    float dg = b_ih[512 + tid] + b_hh[512 + tid];
    float dv = b_ih[768 + tid] + b_hh[768 + tid];
    const float4v* wi = (const float4v*)(w_ih + (size_t)tid * 512);
    const float4v* wg = (const float4v*)(w_ih + (size_t)(512 + tid) * 512);
    const float4v* wo = (const float4v*)(w_ih + (size_t)(768 + tid) * 512);
    for (int k = 0; k < 128; ++k) {
        float4v xv = *(const float4v*)(x1 + k * 4);
        float4v a = wi[k], bq = wg[k], cq = wo[k];
        di += a[0]*xv[0] + a[1]*xv[1] + a[2]*xv[2] + a[3]*xv[3];
        dg += bq[0]*xv[0] + bq[1]*xv[1] + bq[2]*xv[2] + bq[3]*xv[3];
        dv += cq[0]*xv[0] + cq[1]*xv[1] + cq[2]*xv[2] + cq[3]*xv[3];
    }
    float cv = sigf(di) * tanhf_f(dg);
    float hr = sigf(dv) * tanhf_f(cv);
    float pcontrib = fc_w[tid] * hlast[(size_t)b * 256 + tid] + fc_w[256 + tid] * hr;
    red[tid] = pcontrib;
    __syncthreads();
    #pragma unroll
    for (int s = 128; s > 0; s >>= 1) {
        if (tid < s) red[tid] += red[tid + s];
        __syncthreads();
    }
    if (tid == 0) out[b] = red[0] + fc_b[0];
}

// ---------------------------------------------------------------------------
extern "C" void kernel_launch(void* const* d_in, const int* in_sizes, int n_in,
                              void* d_out, int out_size, void* d_ws, size_t ws_size,
                              hipStream_t stream)
{
    const float* x        = (const float*)d_in[0];
    const float* w_ih_l0  = (const float*)d_in[1];
    const float* w_hh_l0  = (const float*)d_in[2];
    const float* b_ih_l0  = (const float*)d_in[3];
    const float* b_hh_l0  = (const float*)d_in[4];
    const float* w_ih_l0r = (const float*)d_in[5];
    const float* w_hh_l0r = (const float*)d_in[6];
    const float* b_ih_l0r = (const float*)d_in[7];
    const float* b_hh_l0r = (const float*)d_in[8];
    const float* w_ih_l1  = (const float*)d_in[9];
    const float* w_hh_l1  = (const float*)d_in[10];
    const float* b_ih_l1  = (const float*)d_in[11];
    const float* b_hh_l1  = (const float*)d_in[12];
    const float* w_ih_l1r = (const float*)d_in[13];
    const float* b_ih_l1r = (const float*)d_in[15];
    const float* b_hh_l1r = (const float*)d_in[16];
    const float* fc_w     = (const float*)d_in[17];
    const float* fc_b     = (const float*)d_in[18];
    float* out = (float*)d_out;
    (void)in_sizes; (void)n_in; (void)out_size; (void)ws_size;

    char* p = (char*)d_ws;
    size_t o = 0;
    auto take = [&](size_t bytes) -> char* {
        char* r = p + o; o += (bytes + 255) & ~(size_t)255; return r;
    };
    uint16_t* Wp_l0f = (uint16_t*)take(64*10*64*8 * 2);
    uint16_t* Wp_l0r = (uint16_t*)take(64*10*64*8 * 2);
    uint16_t* Wp_l1f = (uint16_t*)take(64*8*64*8 * 2);
    uint16_t* Wp_ih1 = (uint16_t*)take(64*16*64*8 * 2);
    float*    bias   = (float*)take(3 * 1024 * 4);
    uint16_t* l0out  = (uint16_t*)take((size_t)TT*BB*512*2);
    uint16_t* xg1p   = (uint16_t*)take((size_t)TT*16*64*64*4*2);
    float*    hlast  = (float*)take(BB * 256 * 4);
    uint32_t* flags  = (uint32_t*)take(96 * 4);              // 64 (L0) + 32 (L1)
    uint16_t* exch0  = (uint16_t*)take((size_t)64 * 4096 * 2);
    uint16_t* exch1  = (uint16_t*)take((size_t)32 * 4096 * 2);

    zero_flags<<<1, 128, 0, stream>>>(flags);

    prepack<<<dim3(2048, 5, 1), 256, 0, stream>>>(
        w_ih_l0, w_hh_l0, w_ih_l0r, w_hh_l0r, w_hh_l1, w_ih_l1,
        b_ih_l0, b_hh_l0, b_ih_l0r, b_hh_l0r, b_ih_l1, b_hh_l1,
        Wp_l0f, Wp_l0r, Wp_l1f, Wp_ih1, bias);

    // layer 0, both directions, gate-split pairs: 2 dirs x 16 tiles x 2 = 64 wgs
    scan_pair<0><<<64, 512, 0, stream>>>(x, Wp_l0f, Wp_l0r, bias, nullptr,
                                         l0out, nullptr, exch0, flags);

    // layer-1 input projection (full-chip GEMM)
    gemm_xg1<<<(TT * BB) / 64, 256, 0, stream>>>(l0out, Wp_ih1, bias + 2048, xg1p);

    // layer 1 forward scan: 16 tiles x 2 halves = 32 wgs
    scan_pair<1><<<32, 512, 0, stream>>>(nullptr, Wp_l1f, nullptr, nullptr, xg1p,
                                         nullptr, hlast, exch1, flags + 64);

    // layer-1 reverse single step + FC
    l1r_fc<<<BB, 256, 0, stream>>>(l0out, w_ih_l1r, b_ih_l1r, b_hh_l1r, hlast, fc_w, fc_b, out);
}